// Round 7
// baseline (328.002 us; speedup 1.0000x reference)
//
#include <hip/hip_runtime.h>
#include <math.h>
#include <float.h>

// Problem dims (fixed by setup_inputs)
#define BB 32
#define TT 2048
#define OO 128
#define CC 80
#define EPSF 1e-7f
#define NT 256
#define SLOTS 8           // columns per thread in LSA
#define CPAD 84           // padded LDS class-row stride (floats)
#define NTILE 8           // cost-kernel t-tiles (TT/NT)
#define ARR_CAP 256       // max ARR steps (leftovers go to Dijkstra)

struct alignas(16) URow { double u; int row; int pad; };   // {u[row4col[j]], row4col[j]}
struct alignas(8)  P2   { int i; int j; };                 // path row, its prior column
struct alignas(16) Cand { double v; int j; int pad; };
struct alignas(16) A3   { double m1; double m2; int j1; int pad; };

// DPP lexicographic-min (val,idx): incoming lanes aggregate strictly-lower
// column ranges -> (tv <= bv) == first-index tie-break. Identity {+inf, MAX}.
template<int CTRL>
__device__ __forceinline__ void dpp_lexmin(double& bv, int& bj) {
    int lo = __double2loint(bv), hi = __double2hiint(bv);
    int tlo = __builtin_amdgcn_update_dpp(0, lo, CTRL, 0xF, 0xF, false);
    int thi = __builtin_amdgcn_update_dpp(0x7FF00000, hi, CTRL, 0xF, 0xF, false);
    int tj  = __builtin_amdgcn_update_dpp(0x7FFFFFFF, bj, CTRL, 0xF, 0xF, false);
    double tv = __hiloint2double(thi, tlo);
    if (tv <= bv) { bv = tv; bj = tj; }
}

// f32 (val,idx) lexmin for the cost kernel's row-min reduction.
template<int CTRL>
__device__ __forceinline__ void dpp_lexmin_f32(float& bv, int& bj) {
    int tlo = __builtin_amdgcn_update_dpp(0x7F800000, __float_as_int(bv), CTRL, 0xF, 0xF, false);
    int tj  = __builtin_amdgcn_update_dpp(0x7FFFFFFF, bj, CTRL, 0xF, 0xF, false);
    float tv = __int_as_float(tlo);
    if (tv < bv || (tv == bv && tj < bj)) { bv = tv; bj = tj; }
}

// Top-2 (m1,j1,m2) merge via DPP. The shr1/2/4/8 + bcast15/31 tree merges
// DISJOINT lane ranges on the lane-63 path, so the top-2 multiset merge is
// exact (no duplicate elements). Identity = {+inf, MAX, +inf}.
template<int CTRL>
__device__ __forceinline__ void dpp_top2(double& m1, int& j1, double& m2) {
    int a1lo = __double2loint(m1), a1hi = __double2hiint(m1);
    int a2lo = __double2loint(m2), a2hi = __double2hiint(m2);
    int b1lo = __builtin_amdgcn_update_dpp(0, a1lo, CTRL, 0xF, 0xF, false);
    int b1hi = __builtin_amdgcn_update_dpp(0x7FF00000, a1hi, CTRL, 0xF, 0xF, false);
    int bj   = __builtin_amdgcn_update_dpp(0x7FFFFFFF, j1, CTRL, 0xF, 0xF, false);
    int b2lo = __builtin_amdgcn_update_dpp(0, a2lo, CTRL, 0xF, 0xF, false);
    int b2hi = __builtin_amdgcn_update_dpp(0x7FF00000, a2hi, CTRL, 0xF, 0xF, false);
    double om1 = __hiloint2double(b1hi, b1lo);
    double om2 = __hiloint2double(b2hi, b2lo);
    bool w = (om1 < m1) || (om1 == m1 && bj < j1);
    double lose1 = w ? m1 : om1;
    double keep2 = w ? om2 : m2;
    if (w) { m1 = om1; j1 = bj; }
    m2 = (lose1 < keep2) ? lose1 : keep2;
}

// ---------------------------------------------------------------------------
// Fused cost kernel (bit-identical math) + per-(b,o) row-min/argmin via f32
// DPP lexmin -> per-wave LDS post -> one barrier -> per-block result written
// plainly to rowmins[b][tile][o] (no atomics, no init needed).
// ---------------------------------------------------------------------------
__global__ __launch_bounds__(NT) void cost_fused_kernel(
    const float* __restrict__ pb, const float* __restrict__ tb,
    const float* __restrict__ cls, const int* __restrict__ tcls,
    float* __restrict__ cost, unsigned long long* __restrict__ rowmins) {
#pragma clang fp contract(off)
    int b = blockIdx.y;
    int tile = blockIdx.x;
    int t0 = tile * NT;
    int tid = threadIdx.x;
    int lane = tid & 63;
    int wave = tid >> 6;

    __shared__ float s_xv[NT * CPAD];
    __shared__ float s_x1[OO], s_y1[OO], s_x2[OO], s_y2[OO], s_w2h2[OO];
    __shared__ int s_tc[OO];
    __shared__ unsigned long long s_rmin[OO * 4];

    const float* cbase = cls + ((size_t)b * TT + t0) * CC;
    #pragma unroll
    for (int k = 0; k < CC / 4; ++k) {   // 20 iters
        int idx4 = (k * NT + tid) * 4;
        float4 vv = *(const float4*)(cbase + idx4);
        int r = idx4 / CC;
        int c = idx4 - r * CC;
        *(float4*)(&s_xv[r * CPAD + c]) = vv;
    }
    if (tid < OO) {
        float4 tbox = ((const float4*)tb)[b * OO + tid];
        float x1 = tbox.x - tbox.z / 2.f;
        float y1 = tbox.y - tbox.w / 2.f;
        float x2 = tbox.x + tbox.z / 2.f;
        float y2 = tbox.y + tbox.w / 2.f;
        s_x1[tid] = x1; s_y1[tid] = y1; s_x2[tid] = x2; s_y2[tid] = y2;
        float w2 = x2 - x1;
        float h2 = (y2 - y1) + EPSF;
        s_w2h2[tid] = w2 * h2;
        s_tc[tid] = tcls[b * OO + tid];
    }
    __syncthreads();

    size_t bt = (size_t)b * TT + t0 + tid;
    float4 pbox = ((const float4*)pb)[bt];
    float b1x1 = pbox.x - pbox.z / 2.f;
    float b1y1 = pbox.y - pbox.w / 2.f;
    float b1x2 = pbox.x + pbox.z / 2.f;
    float b1y2 = pbox.y + pbox.w / 2.f;
    float w1 = b1x2 - b1x1;
    float h1 = (b1y2 - b1y1) + EPSF;
    float w1h1 = w1 * h1;

    const float* xr = &s_xv[tid * CPAD];
    float m = xr[0];
    #pragma unroll
    for (int c = 1; c < CC; ++c) m = fmaxf(m, xr[c]);
    float ssum = 0.f;
    #pragma unroll
    for (int c = 0; c < CC; ++c) ssum += expf(xr[c] - m);
    float ls = logf(ssum);

    float* cbt = cost + (size_t)b * OO * TT + t0;
    for (int o = 0; o < OO; ++o) {
        float b2x1 = s_x1[o], b2y1 = s_y1[o], b2x2 = s_x2[o], b2y2 = s_y2[o];
        float iw = fminf(b1x2, b2x2) - fmaxf(b1x1, b2x1);
        float ih = fminf(b1y2, b2y2) - fmaxf(b1y1, b2y1);
        iw = fmaxf(iw, 0.f);
        ih = fmaxf(ih, 0.f);
        float inter = iw * ih;
        float uni = ((w1h1 + s_w2h2[o]) - inter) + EPSF;
        float iou = inter / uni;
        float cw = fmaxf(b1x2, b2x2) - fminf(b1x1, b2x1);
        float ch = fmaxf(b1y2, b2y2) - fminf(b1y1, b2y1);
        float c_area = (cw * ch) + EPSF;
        float giou = iou - (c_area - uni) / c_area;
        float bbox_loss = 1.0f - giou;

        float xc = xr[s_tc[o]];
        float shifted = xc - m;
        float cls_neg = -(shifted - ls);

        float cval = bbox_loss + cls_neg;
        cbt[(size_t)o * TT + tid] = cval;

        // per-(b,o) wave min/argmin (cval > 0 -> finite, f32 order exact)
        float bvv = cval;
        int bjj = t0 + tid;
        dpp_lexmin_f32<0x111>(bvv, bjj);
        dpp_lexmin_f32<0x112>(bvv, bjj);
        dpp_lexmin_f32<0x114>(bvv, bjj);
        dpp_lexmin_f32<0x118>(bvv, bjj);
        dpp_lexmin_f32<0x142>(bvv, bjj);
        dpp_lexmin_f32<0x143>(bvv, bjj);
        if (lane == 63)
            s_rmin[o * 4 + wave] =
                ((unsigned long long)__float_as_uint(bvv) << 32) | (unsigned)bjj;
    }
    __syncthreads();
    if (tid < OO) {
        unsigned long long r0 = s_rmin[tid * 4 + 0];
        unsigned long long r1 = s_rmin[tid * 4 + 1];
        unsigned long long r2 = s_rmin[tid * 4 + 2];
        unsigned long long r3 = s_rmin[tid * 4 + 3];
        unsigned long long m01 = r0 < r1 ? r0 : r1;
        unsigned long long m23 = r2 < r3 ? r2 : r3;
        rowmins[((size_t)b * NTILE + tile) * OO + tid] = m01 < m23 ? m01 : m23;
    }
}

// ---------------------------------------------------------------------------
// LSA: greedy tight pre-assignment -> LAPJV augmenting row reduction (ARR)
// -> Dijkstra SAP (round-6 core) for leftovers. Duals stay feasible
// (cbar>=0, matched edges tight, v<=0, unmatched cols v=0) through every
// phase, so the result is the optimal assignment.
// ---------------------------------------------------------------------------
__global__ __launch_bounds__(NT) void lsa_kernel(
    const float* __restrict__ cost,
    const unsigned long long* __restrict__ rowmins,
    int* __restrict__ out) {
#pragma clang fp contract(off)
    int b = blockIdx.x;
    int tid = threadIdx.x;
    int lane = tid & 63;
    int wave = tid >> 6;

    __shared__ URow sh_urow[TT];
    __shared__ P2   sh_path2[TT];      // swizzled: col j at [(j&7)*NT + (j>>3)]
    __shared__ int  sh_row4col[TT];
    __shared__ int  sh_claim[TT];
    __shared__ int  sh_col4row[OO];
    __shared__ double sh_u[OO];
    __shared__ int  sh_amin[OO];
    __shared__ int  sh_flag[OO];
    __shared__ int  sh_q[OO + ARR_CAP + 16];  // ARR work queue
    __shared__ int  sh_freelist[OO];
    __shared__ int  sh_selj[OO + 8];
    __shared__ double sh_selm[OO + 8];
    __shared__ int  sh_selrow[OO + 8];
    __shared__ Cand sh_cand[2][4];
    __shared__ A3   sh_arr[4];
    __shared__ int  sh_nfree;
    __shared__ int  sh_qt;

    const float* cb = cost + (size_t)b * OO * TT;
    const int jbase = tid * SLOTS;

    double v_[SLOTS];
    double key[SLOTS];
    #pragma unroll
    for (int s = 0; s < SLOTS; ++s) v_[s] = 0.0;

    // ---- Phase A: u = row minima (combine the 8 tile results) ----
    if (tid < OO) {
        const unsigned long long* p = rowmins + (size_t)b * NTILE * OO + tid;
        unsigned long long best = p[0];
        #pragma unroll
        for (int t = 1; t < NTILE; ++t) {
            unsigned long long x = p[t * OO];
            if (x < best) best = x;
        }
        sh_u[tid] = (double)__uint_as_float((unsigned)(best >> 32));
        sh_amin[tid] = (int)(best & 0xFFFFFFFFull);
        sh_col4row[tid] = -1;
    }
    for (int j = tid; j < TT; j += NT) { sh_row4col[j] = -1; sh_claim[j] = 0x7FFFFFFF; }
    __syncthreads();

    // ---- Phase B: greedy tight pre-assignment (lowest row wins) ----
    if (tid < OO) atomicMin(&sh_claim[sh_amin[tid]], tid);
    __syncthreads();
    if (tid < OO) {
        int j = sh_amin[tid];
        if (sh_claim[j] == tid) { sh_col4row[tid] = j; sh_row4col[j] = tid; }
        sh_flag[tid] = (sh_col4row[tid] < 0) ? 1 : 0;
    }
    __syncthreads();
    if (tid < OO && sh_flag[tid]) {
        int rank = 0;
        for (int o = 0; o < tid; ++o) rank += sh_flag[o];
        sh_q[rank] = tid;
    }
    if (tid == 0) {
        int nf = 0;
        for (int o = 0; o < OO; ++o) nf += sh_flag[o];
        sh_qt = nf;
    }
    __syncthreads();

    // ---- Phase ARR: augmenting row reduction ----
    // For free row i: U1=min_j(c[i][j]-v[j]) at J1, U2=second min. If U1<U2:
    // v[J1] -= (U2-U1), assign i->J1 (tight, u[i]=U2), displaced owner
    // re-queued. Exact ties: skip (left for Dijkstra). Keeps duals feasible.
    int qh = 0, qt = sh_qt, steps = 0;
    while (qh < qt && steps < ARR_CAP) {
        int i = sh_q[qh];
        const float* crow = cb + (size_t)i * TT + jbase;
        float4 c0 = *(const float4*)crow;
        float4 c1 = *(const float4*)(crow + 4);
        float cv[SLOTS] = {c0.x, c0.y, c0.z, c0.w, c1.x, c1.y, c1.z, c1.w};
        double m1 = INFINITY, m2 = INFINITY;
        int j1 = 0x7FFFFFFF;
        #pragma unroll
        for (int s = 0; s < SLOTS; ++s) {
            double r = (double)cv[s] - v_[s];
            bool lt = (r < m1);
            double lose = lt ? m1 : r;
            if (lt) { m1 = r; j1 = jbase + s; }
            if (lose < m2) m2 = lose;
        }
        dpp_top2<0x111>(m1, j1, m2);
        dpp_top2<0x112>(m1, j1, m2);
        dpp_top2<0x114>(m1, j1, m2);
        dpp_top2<0x118>(m1, j1, m2);
        dpp_top2<0x142>(m1, j1, m2);
        dpp_top2<0x143>(m1, j1, m2);
        if (lane == 63) { A3 a; a.m1 = m1; a.m2 = m2; a.j1 = j1; a.pad = 0; sh_arr[wave] = a; }
        __syncthreads();

        A3 a0 = sh_arr[0];
        double U1 = a0.m1, U2 = a0.m2;
        int J1 = a0.j1;
        #pragma unroll
        for (int w = 1; w < 4; ++w) {
            A3 aw = sh_arr[w];
            bool wn = (aw.m1 < U1) || (aw.m1 == U1 && aw.j1 < J1);
            double lose1 = wn ? U1 : aw.m1;
            double keep2 = wn ? aw.m2 : U2;
            if (wn) { U1 = aw.m1; J1 = aw.j1; }
            U2 = (lose1 < keep2) ? lose1 : keep2;
        }
        qh++; steps++;
        if (U1 < U2) {
            if ((J1 >> 3) == tid) {      // v owner updates its register slot
                double d = U2 - U1;
                int sl = J1 & 7;
                #pragma unroll
                for (int ss = 0; ss < SLOTS; ++ss)
                    if (ss == sl) v_[ss] = v_[ss] - d;
            }
            if (tid == 0) {              // tid0 owns all LDS mutations
                int k = sh_row4col[J1];
                sh_row4col[J1] = i;
                sh_col4row[i] = J1;
                sh_u[i] = U2;
                int nqt = qt;
                if (k >= 0) { sh_col4row[k] = -1; sh_q[qt] = k; nqt = qt + 1; }
                sh_qt = nqt;
            }
        } else {
            if (tid == 0) sh_qt = qt;    // tie: skip row, stays free
        }
        __syncthreads();                 // publish mutations + queue tail
        qt = sh_qt;
    }

    // ---- Phase C: rebuild urow + Dijkstra freelist ----
    for (int j = tid; j < TT; j += NT) {
        int r = sh_row4col[j];
        URow t; t.row = r; t.u = (r >= 0) ? sh_u[r] : 0.0; t.pad = 0;
        sh_urow[j] = t;
    }
    if (tid < OO) sh_flag[tid] = (sh_col4row[tid] < 0) ? 1 : 0;
    __syncthreads();
    if (tid < OO && sh_flag[tid]) {
        int rank = 0;
        for (int o = 0; o < tid; ++o) rank += sh_flag[o];
        sh_freelist[rank] = tid;
    }
    if (tid == 0) {
        int nf = 0;
        for (int o = 0; o < OO; ++o) nf += sh_flag[o];
        sh_nfree = nf;
    }
    __syncthreads();
    int nfree = sh_nfree;

    // ---- Phase D: Dijkstra SAP (round-6 core) ----
    int par = 0;
    for (int fi = 0; fi < nfree; ++fi) {
        int cur = sh_freelist[fi];

        #pragma unroll
        for (int s = 0; s < SLOTS; ++s) key[s] = INFINITY;
        int selbits = 0;
        double mv = 0.0;
        int i = cur, jc = -1;
        double ui = sh_u[cur];
        const float* crow0 = cb + (size_t)i * TT + jbase;
        float4 c0 = *(const float4*)crow0;
        float4 c1 = *(const float4*)(crow0 + 4);
        int L = 0, sink;

        while (true) {
            float cv[SLOTS] = {c0.x, c0.y, c0.z, c0.w, c1.x, c1.y, c1.z, c1.w};

            double bv = INFINITY;
            int bj = TT;
            #pragma unroll
            for (int s = 0; s < SLOTS; ++s) {
                if (!((selbits >> s) & 1)) {
                    double r = ((mv + (double)cv[s]) - ui) - v_[s];
                    if (r < key[s]) {
                        key[s] = r;
                        P2 p; p.i = i; p.j = jc;
                        sh_path2[s * NT + tid] = p;
                    }
                    double kk = key[s];
                    if (kk < bv) { bv = kk; bj = jbase + s; }
                }
            }
            dpp_lexmin<0x111>(bv, bj);
            dpp_lexmin<0x112>(bv, bj);
            dpp_lexmin<0x114>(bv, bj);
            dpp_lexmin<0x118>(bv, bj);
            dpp_lexmin<0x142>(bv, bj);
            dpp_lexmin<0x143>(bv, bj);
            int rlo = __builtin_amdgcn_readlane(__double2loint(bv), 63);
            int rhi = __builtin_amdgcn_readlane(__double2hiint(bv), 63);
            double wv = __hiloint2double(rhi, rlo);
            int wj = __builtin_amdgcn_readlane(bj, 63);

            par ^= 1;
            if (lane == 0) {
                Cand c; c.v = wv; c.j = wj; c.pad = 0;
                sh_cand[par][wave] = c;
            }
            __syncthreads();

            Cand cc = sh_cand[par][0];
            double MV = cc.v; int BJ = cc.j;
            #pragma unroll
            for (int w = 1; w < 4; ++w) {
                Cand c2 = sh_cand[par][w];
                if (c2.v < MV || (c2.v == MV && c2.j < BJ)) { MV = c2.v; BJ = c2.j; }
            }
            mv = MV;
            if ((BJ >> 3) == tid) selbits |= 1 << (BJ & 7);
            if (tid == 0) sh_selj[L] = BJ;

            URow ur = sh_urow[BJ];
            if (ur.row < 0) { sink = BJ; break; }
            if (tid == 0) { sh_selm[L] = MV; sh_selrow[L] = ur.row; }
            i = ur.row; ui = ur.u; jc = BJ;
            L++;
            const float* crow = cb + (size_t)i * TT + jbase;
            c0 = *(const float4*)crow;
            c1 = *(const float4*)(crow + 4);
        }

        double M = mv;
        #pragma unroll
        for (int s = 0; s < SLOTS; ++s)
            if ((selbits >> s) & 1) v_[s] = v_[s] - (M - key[s]);
        for (int k = tid; k < L; k += NT)
            sh_u[sh_selrow[k]] = sh_u[sh_selrow[k]] + (M - sh_selm[k]);
        if (tid == 0) {
            sh_u[cur] = sh_u[cur] + M;
            int j = sink;
            while (true) {
                P2 p = sh_path2[(j & 7) * NT + (j >> 3)];
                int ii = p.i;
                sh_row4col[j] = ii;
                sh_col4row[ii] = j;
                if (ii == cur) break;
                j = p.j;
            }
        }
        __syncthreads();
        if (tid <= L) {
            int j = sh_selj[tid];
            int r = sh_row4col[j];
            URow t; t.u = sh_u[r]; t.row = r; t.pad = 0;
            sh_urow[j] = t;
        }
        __syncthreads();
    }

    // order = argsort(col4row); pred_idx = col4row[order]; tgt_idx = order
    if (tid < OO) {
        int my = sh_col4row[tid];
        int rank = 0;
        for (int o = 0; o < OO; ++o) rank += (sh_col4row[o] < my) ? 1 : 0;
        out[(size_t)b * OO + rank] = my;         // pred_idx
        out[(size_t)(BB + b) * OO + rank] = tid; // tgt_idx
    }
}

// ---------------------------------------------------------------------------
extern "C" void kernel_launch(void* const* d_in, const int* in_sizes, int n_in,
                              void* d_out, int out_size, void* d_ws, size_t ws_size,
                              hipStream_t stream) {
    const float* pred_bboxes = (const float*)d_in[0];    // [B,T,4]
    const float* target_bboxes = (const float*)d_in[1];  // [B,O,4]
    const float* pred_classes = (const float*)d_in[2];   // [B,T,C]
    const int* target_classes = (const int*)d_in[3];     // [B,O]
    int* out = (int*)d_out;                              // [2,B,O] int32

    float* cost = (float*)d_ws;  // [B][O][T] fp32 (32 MB)
    unsigned long long* rowmins =
        (unsigned long long*)(cost + (size_t)BB * OO * TT);  // [B][NTILE][O]

    dim3 cgrid(NTILE, BB);
    cost_fused_kernel<<<cgrid, NT, 0, stream>>>(pred_bboxes, target_bboxes,
                                                pred_classes, target_classes,
                                                cost, rowmins);
    lsa_kernel<<<BB, NT, 0, stream>>>(cost, rowmins, out);
}

// Round 8
// 295.638 us; speedup vs baseline: 1.1095x; 1.1095x over previous
//
#include <hip/hip_runtime.h>
#include <math.h>
#include <float.h>

// Problem dims (fixed by setup_inputs)
#define BB 32
#define TT 2048
#define OO 128
#define CC 80
#define EPSF 1e-7f
#define NT 256
#define SLOTS 8           // columns per thread in LSA
#define CPAD 84           // padded LDS class-row stride (floats)
#define NTILE 8           // cost t-tiles (TT/NT)

struct alignas(16) URow { double u; int row; int pad; };   // {u[row4col[j]], row4col[j]}
struct alignas(8)  P2   { int i; int j; };                 // path row, its prior column
struct alignas(16) Cand { double v; int j; int pad; };

// DPP lexicographic-min (val,idx): incoming lanes aggregate strictly-lower
// column ranges -> (tv <= bv) == first-index tie-break. Identity {+inf, MAX}.
template<int CTRL>
__device__ __forceinline__ void dpp_lexmin(double& bv, int& bj) {
    int lo = __double2loint(bv), hi = __double2hiint(bv);
    int tlo = __builtin_amdgcn_update_dpp(0, lo, CTRL, 0xF, 0xF, false);
    int thi = __builtin_amdgcn_update_dpp(0x7FF00000, hi, CTRL, 0xF, 0xF, false);
    int tj  = __builtin_amdgcn_update_dpp(0x7FFFFFFF, bj, CTRL, 0xF, 0xF, false);
    double tv = __hiloint2double(thi, tlo);
    if (tv <= bv) { bv = tv; bj = tj; }
}

// f32 (val,idx) lexmin for the cost phase's row-min reduction.
template<int CTRL>
__device__ __forceinline__ void dpp_lexmin_f32(float& bv, int& bj) {
    int tlo = __builtin_amdgcn_update_dpp(0x7F800000, __float_as_int(bv), CTRL, 0xF, 0xF, false);
    int tj  = __builtin_amdgcn_update_dpp(0x7FFFFFFF, bj, CTRL, 0xF, 0xF, false);
    float tv = __int_as_float(tlo);
    if (tv < bv || (tv == bv && tj < bj)) { bv = tv; bj = tj; }
}

// LDS is phase-exclusive: cost staging first, LSA state after (one block
// never needs both live simultaneously; barrier separates the phases).
union SM {
    struct {
        float xv[NT * CPAD];                       // 86016 B
        float x1[OO], y1[OO], x2[OO], y2[OO], w2h2[OO];
        int   tc[OO];
        unsigned long long rmin[OO * 4];
    } c;
    struct {
        URow   urow[TT];                           // 32768 B
        P2     path2[TT];                          // 16384 B (swizzled)
        int    row4col[TT];
        int    claim[TT];
        int    col4row[OO];
        double u[OO];
        int    amin[OO];
        int    flag[OO];
        int    freelist[OO];
        int    selj[OO + 8];
        double selm[OO + 8];
        int    selrow[OO + 8];
        Cand   cand[2][4];
        int    nfree;
    } l;
};

// ---------------------------------------------------------------------------
// Fused kernel. All 256 blocks: cost tile (bit-identical math) + per-tile
// row minima -> release-signal cnt[b]. Tile-0 blocks then acquire-spin for
// their batch's 8 tiles and run the round-6 JV LSA (greedy tight
// pre-assignment + Dijkstra SAP). Device-scope atomics per G16.
// ---------------------------------------------------------------------------
__global__ __launch_bounds__(NT) void hung_fused_kernel(
    const float* __restrict__ pb, const float* __restrict__ tb,
    const float* __restrict__ cls, const int* __restrict__ tcls,
    float* __restrict__ cost, unsigned long long* __restrict__ rowmins,
    int* __restrict__ cnt, int* __restrict__ out) {
#pragma clang fp contract(off)
    __shared__ SM sm;

    int bx = blockIdx.x;
    int b = bx >> 3;
    int tile = bx & 7;
    int t0 = tile * NT;
    int tid = threadIdx.x;
    int lane = tid & 63;
    int wave = tid >> 6;

    // ======================= Phase 1: cost tile =======================
    {
        const float* cbase = cls + ((size_t)b * TT + t0) * CC;
        #pragma unroll
        for (int k = 0; k < CC / 4; ++k) {   // 20 iters
            int idx4 = (k * NT + tid) * 4;
            float4 vv = *(const float4*)(cbase + idx4);
            int r = idx4 / CC;
            int c = idx4 - r * CC;
            *(float4*)(&sm.c.xv[r * CPAD + c]) = vv;
        }
        if (tid < OO) {
            float4 tbox = ((const float4*)tb)[b * OO + tid];
            float x1 = tbox.x - tbox.z / 2.f;
            float y1 = tbox.y - tbox.w / 2.f;
            float x2 = tbox.x + tbox.z / 2.f;
            float y2 = tbox.y + tbox.w / 2.f;
            sm.c.x1[tid] = x1; sm.c.y1[tid] = y1;
            sm.c.x2[tid] = x2; sm.c.y2[tid] = y2;
            float w2 = x2 - x1;
            float h2 = (y2 - y1) + EPSF;
            sm.c.w2h2[tid] = w2 * h2;
            sm.c.tc[tid] = tcls[b * OO + tid];
        }
        __syncthreads();

        size_t bt = (size_t)b * TT + t0 + tid;
        float4 pbox = ((const float4*)pb)[bt];
        float b1x1 = pbox.x - pbox.z / 2.f;
        float b1y1 = pbox.y - pbox.w / 2.f;
        float b1x2 = pbox.x + pbox.z / 2.f;
        float b1y2 = pbox.y + pbox.w / 2.f;
        float w1 = b1x2 - b1x1;
        float h1 = (b1y2 - b1y1) + EPSF;
        float w1h1 = w1 * h1;

        const float* xr = &sm.c.xv[tid * CPAD];
        float m = xr[0];
        #pragma unroll
        for (int c = 1; c < CC; ++c) m = fmaxf(m, xr[c]);
        float ssum = 0.f;
        #pragma unroll
        for (int c = 0; c < CC; ++c) ssum += expf(xr[c] - m);
        float ls = logf(ssum);

        float* cbt = cost + (size_t)b * OO * TT + t0;
        for (int o = 0; o < OO; ++o) {
            float b2x1 = sm.c.x1[o], b2y1 = sm.c.y1[o];
            float b2x2 = sm.c.x2[o], b2y2 = sm.c.y2[o];
            float iw = fminf(b1x2, b2x2) - fmaxf(b1x1, b2x1);
            float ih = fminf(b1y2, b2y2) - fmaxf(b1y1, b2y1);
            iw = fmaxf(iw, 0.f);
            ih = fmaxf(ih, 0.f);
            float inter = iw * ih;
            float uni = ((w1h1 + sm.c.w2h2[o]) - inter) + EPSF;
            float iou = inter / uni;
            float cw = fmaxf(b1x2, b2x2) - fminf(b1x1, b2x1);
            float ch = fmaxf(b1y2, b2y2) - fminf(b1y1, b2y1);
            float c_area = (cw * ch) + EPSF;
            float giou = iou - (c_area - uni) / c_area;
            float bbox_loss = 1.0f - giou;

            float xc = xr[sm.c.tc[o]];
            float shifted = xc - m;
            float cls_neg = -(shifted - ls);

            float cval = bbox_loss + cls_neg;
            cbt[(size_t)o * TT + tid] = cval;

            float bvv = cval;
            int bjj = t0 + tid;
            dpp_lexmin_f32<0x111>(bvv, bjj);
            dpp_lexmin_f32<0x112>(bvv, bjj);
            dpp_lexmin_f32<0x114>(bvv, bjj);
            dpp_lexmin_f32<0x118>(bvv, bjj);
            dpp_lexmin_f32<0x142>(bvv, bjj);
            dpp_lexmin_f32<0x143>(bvv, bjj);
            if (lane == 63)
                sm.c.rmin[o * 4 + wave] =
                    ((unsigned long long)__float_as_uint(bvv) << 32) | (unsigned)bjj;
        }
        __syncthreads();
        if (tid < OO) {
            unsigned long long r0 = sm.c.rmin[tid * 4 + 0];
            unsigned long long r1 = sm.c.rmin[tid * 4 + 1];
            unsigned long long r2 = sm.c.rmin[tid * 4 + 2];
            unsigned long long r3 = sm.c.rmin[tid * 4 + 3];
            unsigned long long m01 = r0 < r1 ? r0 : r1;
            unsigned long long m23 = r2 < r3 ? r2 : r3;
            rowmins[((size_t)b * NTILE + tile) * OO + tid] = m01 < m23 ? m01 : m23;
        }
        __syncthreads();   // __syncthreads drains vmcnt(0): all global stores issued
        if (tid == 0)      // device-scope release: cost+rowmins visible before count
            __hip_atomic_fetch_add(&cnt[b], 1, __ATOMIC_RELEASE,
                                   __HIP_MEMORY_SCOPE_AGENT);
    }

    if (tile != 0) return;   // 224 producer-only blocks exit

    // ============ Phase 2 (tile-0 blocks): wait for siblings ============
    if (tid == 0) {
        while (__hip_atomic_load(&cnt[b], __ATOMIC_ACQUIRE,
                                 __HIP_MEMORY_SCOPE_AGENT) < NTILE)
            __builtin_amdgcn_s_sleep(2);
    }
    __syncthreads();   // all threads see post-acquire state

    // ======================= Phase 3: LSA (round-6 core) =======================
    const float* cb = cost + (size_t)b * OO * TT;
    const int jbase = tid * SLOTS;

    double v_[SLOTS];
    double key[SLOTS];
    #pragma unroll
    for (int s = 0; s < SLOTS; ++s) v_[s] = 0.0;

    // ---- Phase A: u = row minima (combine the 8 tile results) ----
    if (tid < OO) {
        const unsigned long long* p = rowmins + (size_t)b * NTILE * OO + tid;
        unsigned long long best = p[0];
        #pragma unroll
        for (int t = 1; t < NTILE; ++t) {
            unsigned long long x = p[t * OO];
            if (x < best) best = x;
        }
        sm.l.u[tid] = (double)__uint_as_float((unsigned)(best >> 32));
        sm.l.amin[tid] = (int)(best & 0xFFFFFFFFull);
        sm.l.col4row[tid] = -1;
    }
    for (int j = tid; j < TT; j += NT) { sm.l.row4col[j] = -1; sm.l.claim[j] = 0x7FFFFFFF; }
    __syncthreads();

    // ---- Phase B: greedy tight pre-assignment (lowest row wins) ----
    if (tid < OO) atomicMin(&sm.l.claim[sm.l.amin[tid]], tid);
    __syncthreads();
    if (tid < OO) {
        int j = sm.l.amin[tid];
        if (sm.l.claim[j] == tid) { sm.l.col4row[tid] = j; sm.l.row4col[j] = tid; }
    }
    __syncthreads();

    // ---- Phase C: urow init + free-row list ----
    for (int j = tid; j < TT; j += NT) {
        int r = sm.l.row4col[j];
        URow t; t.row = r; t.u = (r >= 0) ? sm.l.u[r] : 0.0; t.pad = 0;
        sm.l.urow[j] = t;
    }
    if (tid < OO) sm.l.flag[tid] = (sm.l.col4row[tid] < 0) ? 1 : 0;
    __syncthreads();
    if (tid < OO && sm.l.flag[tid]) {
        int rank = 0;
        for (int o = 0; o < tid; ++o) rank += sm.l.flag[o];
        sm.l.freelist[rank] = tid;
    }
    if (tid == 0) {
        int nf = 0;
        for (int o = 0; o < OO; ++o) nf += sm.l.flag[o];
        sm.l.nfree = nf;
    }
    __syncthreads();
    int nfree = sm.l.nfree;

    // ---- Phase D: Dijkstra SAP ----
    int par = 0;
    for (int fi = 0; fi < nfree; ++fi) {
        int cur = sm.l.freelist[fi];

        #pragma unroll
        for (int s = 0; s < SLOTS; ++s) key[s] = INFINITY;
        int selbits = 0;
        double mv = 0.0;
        int i = cur, jc = -1;
        double ui = sm.l.u[cur];
        const float* crow0 = cb + (size_t)i * TT + jbase;
        float4 c0 = *(const float4*)crow0;
        float4 c1 = *(const float4*)(crow0 + 4);
        int L = 0, sink;

        while (true) {
            float cv[SLOTS] = {c0.x, c0.y, c0.z, c0.w, c1.x, c1.y, c1.z, c1.w};

            double bv = INFINITY;
            int bj = TT;
            #pragma unroll
            for (int s = 0; s < SLOTS; ++s) {
                if (!((selbits >> s) & 1)) {
                    double r = ((mv + (double)cv[s]) - ui) - v_[s];
                    if (r < key[s]) {
                        key[s] = r;
                        P2 p; p.i = i; p.j = jc;
                        sm.l.path2[s * NT + tid] = p;
                    }
                    double kk = key[s];
                    if (kk < bv) { bv = kk; bj = jbase + s; }
                }
            }
            dpp_lexmin<0x111>(bv, bj);
            dpp_lexmin<0x112>(bv, bj);
            dpp_lexmin<0x114>(bv, bj);
            dpp_lexmin<0x118>(bv, bj);
            dpp_lexmin<0x142>(bv, bj);
            dpp_lexmin<0x143>(bv, bj);
            int rlo = __builtin_amdgcn_readlane(__double2loint(bv), 63);
            int rhi = __builtin_amdgcn_readlane(__double2hiint(bv), 63);
            double wv = __hiloint2double(rhi, rlo);
            int wj = __builtin_amdgcn_readlane(bj, 63);

            par ^= 1;
            if (lane == 0) {
                Cand c; c.v = wv; c.j = wj; c.pad = 0;
                sm.l.cand[par][wave] = c;
            }
            __syncthreads();

            Cand cc = sm.l.cand[par][0];
            double MV = cc.v; int BJ = cc.j;
            #pragma unroll
            for (int w = 1; w < 4; ++w) {
                Cand c2 = sm.l.cand[par][w];
                if (c2.v < MV || (c2.v == MV && c2.j < BJ)) { MV = c2.v; BJ = c2.j; }
            }
            mv = MV;
            if ((BJ >> 3) == tid) selbits |= 1 << (BJ & 7);
            if (tid == 0) sm.l.selj[L] = BJ;

            URow ur = sm.l.urow[BJ];
            if (ur.row < 0) { sink = BJ; break; }
            if (tid == 0) { sm.l.selm[L] = MV; sm.l.selrow[L] = ur.row; }
            i = ur.row; ui = ur.u; jc = BJ;
            L++;
            const float* crow = cb + (size_t)i * TT + jbase;
            c0 = *(const float4*)crow;
            c1 = *(const float4*)(crow + 4);
        }

        double M = mv;
        #pragma unroll
        for (int s = 0; s < SLOTS; ++s)
            if ((selbits >> s) & 1) v_[s] = v_[s] - (M - key[s]);
        for (int k = tid; k < L; k += NT)
            sm.l.u[sm.l.selrow[k]] = sm.l.u[sm.l.selrow[k]] + (M - sm.l.selm[k]);
        if (tid == 0) {
            sm.l.u[cur] = sm.l.u[cur] + M;
            int j = sink;
            while (true) {
                P2 p = sm.l.path2[(j & 7) * NT + (j >> 3)];
                int ii = p.i;
                sm.l.row4col[j] = ii;
                sm.l.col4row[ii] = j;
                if (ii == cur) break;
                j = p.j;
            }
        }
        __syncthreads();
        if (tid <= L) {
            int j = sm.l.selj[tid];
            int r = sm.l.row4col[j];
            URow t; t.u = sm.l.u[r]; t.row = r; t.pad = 0;
            sm.l.urow[j] = t;
        }
        __syncthreads();
    }

    // order = argsort(col4row); pred_idx = col4row[order]; tgt_idx = order
    if (tid < OO) {
        int my = sm.l.col4row[tid];
        int rank = 0;
        for (int o = 0; o < OO; ++o) rank += (sm.l.col4row[o] < my) ? 1 : 0;
        out[(size_t)b * OO + rank] = my;         // pred_idx
        out[(size_t)(BB + b) * OO + rank] = tid; // tgt_idx
    }
}

// ---------------------------------------------------------------------------
extern "C" void kernel_launch(void* const* d_in, const int* in_sizes, int n_in,
                              void* d_out, int out_size, void* d_ws, size_t ws_size,
                              hipStream_t stream) {
    const float* pred_bboxes = (const float*)d_in[0];    // [B,T,4]
    const float* target_bboxes = (const float*)d_in[1];  // [B,O,4]
    const float* pred_classes = (const float*)d_in[2];   // [B,T,C]
    const int* target_classes = (const int*)d_in[3];     // [B,O]
    int* out = (int*)d_out;                              // [2,B,O] int32

    float* cost = (float*)d_ws;  // [B][O][T] fp32 (32 MB)
    unsigned long long* rowmins =
        (unsigned long long*)(cost + (size_t)BB * OO * TT);  // [B][NTILE][O]
    int* cnt = (int*)(rowmins + (size_t)BB * NTILE * OO);    // [B]

    hipMemsetAsync(cnt, 0, BB * sizeof(int), stream);        // d_ws is 0xAA-poisoned

    hung_fused_kernel<<<BB * NTILE, NT, 0, stream>>>(
        pred_bboxes, target_bboxes, pred_classes, target_classes,
        cost, rowmins, cnt, out);
}

// Round 9
// 289.457 us; speedup vs baseline: 1.1332x; 1.0214x over previous
//
#include <hip/hip_runtime.h>
#include <math.h>
#include <float.h>

// Problem dims (fixed by setup_inputs)
#define BB 32
#define TT 2048
#define OO 128
#define CC 80
#define EPSF 1e-7f
#define NT 256
#define SLOTS 8           // columns per thread in LSA
#define CPAD 81           // LDS class-row stride: 81%32=17, gcd(17,32)=1 -> conflict-free
#define NTILE 8           // cost t-tiles (TT/NT)

struct alignas(16) URow { double u; int row; int pad; };   // {u[row4col[j]], row4col[j]}
struct alignas(8)  P2   { int i; int j; };                 // path row, its prior column
struct alignas(16) Cand { double v; int j; int pad; };

// DPP lexicographic-min (val,idx): incoming lanes aggregate strictly-lower
// column ranges -> (tv <= bv) == first-index tie-break. Identity {+inf, MAX}.
template<int CTRL>
__device__ __forceinline__ void dpp_lexmin(double& bv, int& bj) {
    int lo = __double2loint(bv), hi = __double2hiint(bv);
    int tlo = __builtin_amdgcn_update_dpp(0, lo, CTRL, 0xF, 0xF, false);
    int thi = __builtin_amdgcn_update_dpp(0x7FF00000, hi, CTRL, 0xF, 0xF, false);
    int tj  = __builtin_amdgcn_update_dpp(0x7FFFFFFF, bj, CTRL, 0xF, 0xF, false);
    double tv = __hiloint2double(thi, tlo);
    if (tv <= bv) { bv = tv; bj = tj; }
}

// f32 (val,idx) lexmin for the cost phase's row-min reduction.
template<int CTRL>
__device__ __forceinline__ void dpp_lexmin_f32(float& bv, int& bj) {
    int tlo = __builtin_amdgcn_update_dpp(0x7F800000, __float_as_int(bv), CTRL, 0xF, 0xF, false);
    int tj  = __builtin_amdgcn_update_dpp(0x7FFFFFFF, bj, CTRL, 0xF, 0xF, false);
    float tv = __int_as_float(tlo);
    if (tv < bv || (tv == bv && tj < bj)) { bv = tv; bj = tj; }
}

// LDS is phase-exclusive: cost staging first, LSA state after.
union SM {
    struct {
        float  xv[NT * CPAD];                      // 82944 B
        float4 box[OO];                            // {x1,y1,x2,y2}
        float2 wt[OO];                             // {w2h2, tc-as-float-bits}
        unsigned long long rmin[OO * 4];
    } c;
    struct {
        URow   urow[TT];
        P2     path2[TT];                          // swizzled
        int    row4col[TT];
        int    claim[TT];
        int    col4row[OO];
        double u[OO];
        int    amin[OO];
        int    flag[OO];
        int    freelist[OO];
        int    selj[OO + 8];
        double selm[OO + 8];
        int    selrow[OO + 8];
        Cand   cand[2][4];
        int    nfree;
    } l;
};

// ---------------------------------------------------------------------------
// Fused kernel, XCD-matched mapping: b = bx&31, tile = bx>>5. Batch b's 8
// producer tiles and its LSA block all satisfy bx % 8 == b % 8 -> same XCD
// under round-robin dispatch; 4 batches x 1 MB slice = the XCD's 4 MB L2.
// Producers release-signal cnt[b]; tile-0 blocks acquire-spin then run the
// round-6 JV LSA (greedy tight pre-assignment + Dijkstra SAP).
// ---------------------------------------------------------------------------
__global__ __launch_bounds__(NT) void hung_fused_kernel(
    const float* __restrict__ pb, const float* __restrict__ tb,
    const float* __restrict__ cls, const int* __restrict__ tcls,
    float* __restrict__ cost, unsigned long long* __restrict__ rowmins,
    int* __restrict__ cnt, int* __restrict__ out) {
#pragma clang fp contract(off)
    __shared__ SM sm;

    int bx = blockIdx.x;
    int b = bx & 31;
    int tile = bx >> 5;
    int t0 = tile * NT;
    int tid = threadIdx.x;
    int lane = tid & 63;
    int wave = tid >> 6;

    // ======================= Phase 1: cost tile =======================
    {
        const float* cbase = cls + ((size_t)b * TT + t0) * CC;
        #pragma unroll
        for (int k = 0; k < CC / 4; ++k) {   // 20 iters
            int idx4 = (k * NT + tid) * 4;
            float4 vv = *(const float4*)(cbase + idx4);
            int r = idx4 / CC;
            int c = idx4 - r * CC;
            float* dst = &sm.c.xv[r * CPAD + c];
            dst[0] = vv.x; dst[1] = vv.y; dst[2] = vv.z; dst[3] = vv.w;
        }
        if (tid < OO) {
            float4 tbox = ((const float4*)tb)[b * OO + tid];
            float x1 = tbox.x - tbox.z / 2.f;
            float y1 = tbox.y - tbox.w / 2.f;
            float x2 = tbox.x + tbox.z / 2.f;
            float y2 = tbox.y + tbox.w / 2.f;
            float4 bb; bb.x = x1; bb.y = y1; bb.z = x2; bb.w = y2;
            sm.c.box[tid] = bb;
            float w2 = x2 - x1;
            float h2 = (y2 - y1) + EPSF;
            float2 wt; wt.x = w2 * h2;
            wt.y = __int_as_float(tcls[b * OO + tid]);
            sm.c.wt[tid] = wt;
        }
        __syncthreads();

        size_t bt = (size_t)b * TT + t0 + tid;
        float4 pbox = ((const float4*)pb)[bt];
        float b1x1 = pbox.x - pbox.z / 2.f;
        float b1y1 = pbox.y - pbox.w / 2.f;
        float b1x2 = pbox.x + pbox.z / 2.f;
        float b1y2 = pbox.y + pbox.w / 2.f;
        float w1 = b1x2 - b1x1;
        float h1 = (b1y2 - b1y1) + EPSF;
        float w1h1 = w1 * h1;

        const float* xr = &sm.c.xv[tid * CPAD];
        float m = xr[0];
        #pragma unroll
        for (int c = 1; c < CC; ++c) m = fmaxf(m, xr[c]);
        float ssum = 0.f;
        #pragma unroll
        for (int c = 0; c < CC; ++c) ssum += expf(xr[c] - m);
        float ls = logf(ssum);

        float* cbt = cost + (size_t)b * OO * TT + t0;
        for (int o = 0; o < OO; ++o) {
            float4 bb = sm.c.box[o];        // one b128 broadcast
            float2 wt = sm.c.wt[o];         // one b64 broadcast
            float b2x1 = bb.x, b2y1 = bb.y, b2x2 = bb.z, b2y2 = bb.w;
            float iw = fminf(b1x2, b2x2) - fmaxf(b1x1, b2x1);
            float ih = fminf(b1y2, b2y2) - fmaxf(b1y1, b2y1);
            iw = fmaxf(iw, 0.f);
            ih = fmaxf(ih, 0.f);
            float inter = iw * ih;
            float uni = ((w1h1 + wt.x) - inter) + EPSF;
            float iou = inter / uni;
            float cw = fmaxf(b1x2, b2x2) - fminf(b1x1, b2x1);
            float ch = fmaxf(b1y2, b2y2) - fminf(b1y1, b2y1);
            float c_area = (cw * ch) + EPSF;
            float giou = iou - (c_area - uni) / c_area;
            float bbox_loss = 1.0f - giou;

            float xc = xr[__float_as_int(wt.y)];   // conflict-free (stride 81)
            float shifted = xc - m;
            float cls_neg = -(shifted - ls);

            float cval = bbox_loss + cls_neg;
            cbt[(size_t)o * TT + tid] = cval;

            float bvv = cval;
            int bjj = t0 + tid;
            dpp_lexmin_f32<0x111>(bvv, bjj);
            dpp_lexmin_f32<0x112>(bvv, bjj);
            dpp_lexmin_f32<0x114>(bvv, bjj);
            dpp_lexmin_f32<0x118>(bvv, bjj);
            dpp_lexmin_f32<0x142>(bvv, bjj);
            dpp_lexmin_f32<0x143>(bvv, bjj);
            if (lane == 63)
                sm.c.rmin[o * 4 + wave] =
                    ((unsigned long long)__float_as_uint(bvv) << 32) | (unsigned)bjj;
        }
        __syncthreads();
        if (tid < OO) {
            unsigned long long r0 = sm.c.rmin[tid * 4 + 0];
            unsigned long long r1 = sm.c.rmin[tid * 4 + 1];
            unsigned long long r2 = sm.c.rmin[tid * 4 + 2];
            unsigned long long r3 = sm.c.rmin[tid * 4 + 3];
            unsigned long long m01 = r0 < r1 ? r0 : r1;
            unsigned long long m23 = r2 < r3 ? r2 : r3;
            rowmins[((size_t)b * NTILE + tile) * OO + tid] = m01 < m23 ? m01 : m23;
        }
        __syncthreads();   // drains vmcnt(0): all global stores issued
        if (tid == 0)      // agent-scope release: cost+rowmins visible first
            __hip_atomic_fetch_add(&cnt[b], 1, __ATOMIC_RELEASE,
                                   __HIP_MEMORY_SCOPE_AGENT);
    }

    if (tile != 0) return;   // 224 producer-only blocks exit

    // ============ Phase 2 (tile-0 blocks): wait for siblings ============
    if (tid == 0) {
        while (__hip_atomic_load(&cnt[b], __ATOMIC_ACQUIRE,
                                 __HIP_MEMORY_SCOPE_AGENT) < NTILE)
            __builtin_amdgcn_s_sleep(2);
    }
    __syncthreads();   // all threads see post-acquire state

    // ======================= Phase 3: LSA (round-6 core) =======================
    const float* cb = cost + (size_t)b * OO * TT;
    const int jbase = tid * SLOTS;

    double v_[SLOTS];
    double key[SLOTS];
    #pragma unroll
    for (int s = 0; s < SLOTS; ++s) v_[s] = 0.0;

    // ---- Phase A: u = row minima (combine the 8 tile results) ----
    if (tid < OO) {
        const unsigned long long* p = rowmins + (size_t)b * NTILE * OO + tid;
        unsigned long long best = p[0];
        #pragma unroll
        for (int t = 1; t < NTILE; ++t) {
            unsigned long long x = p[t * OO];
            if (x < best) best = x;
        }
        sm.l.u[tid] = (double)__uint_as_float((unsigned)(best >> 32));
        sm.l.amin[tid] = (int)(best & 0xFFFFFFFFull);
        sm.l.col4row[tid] = -1;
    }
    for (int j = tid; j < TT; j += NT) { sm.l.row4col[j] = -1; sm.l.claim[j] = 0x7FFFFFFF; }
    __syncthreads();

    // ---- Phase B: greedy tight pre-assignment (lowest row wins) ----
    if (tid < OO) atomicMin(&sm.l.claim[sm.l.amin[tid]], tid);
    __syncthreads();
    if (tid < OO) {
        int j = sm.l.amin[tid];
        if (sm.l.claim[j] == tid) { sm.l.col4row[tid] = j; sm.l.row4col[j] = tid; }
    }
    __syncthreads();

    // ---- Phase C: urow init + free-row list ----
    for (int j = tid; j < TT; j += NT) {
        int r = sm.l.row4col[j];
        URow t; t.row = r; t.u = (r >= 0) ? sm.l.u[r] : 0.0; t.pad = 0;
        sm.l.urow[j] = t;
    }
    if (tid < OO) sm.l.flag[tid] = (sm.l.col4row[tid] < 0) ? 1 : 0;
    __syncthreads();
    if (tid < OO && sm.l.flag[tid]) {
        int rank = 0;
        for (int o = 0; o < tid; ++o) rank += sm.l.flag[o];
        sm.l.freelist[rank] = tid;
    }
    if (tid == 0) {
        int nf = 0;
        for (int o = 0; o < OO; ++o) nf += sm.l.flag[o];
        sm.l.nfree = nf;
    }
    __syncthreads();
    int nfree = sm.l.nfree;

    // ---- Phase D: Dijkstra SAP ----
    int par = 0;
    for (int fi = 0; fi < nfree; ++fi) {
        int cur = sm.l.freelist[fi];

        #pragma unroll
        for (int s = 0; s < SLOTS; ++s) key[s] = INFINITY;
        int selbits = 0;
        double mv = 0.0;
        int i = cur, jc = -1;
        double ui = sm.l.u[cur];
        const float* crow0 = cb + (size_t)i * TT + jbase;
        float4 c0 = *(const float4*)crow0;
        float4 c1 = *(const float4*)(crow0 + 4);
        int L = 0, sink;

        while (true) {
            float cv[SLOTS] = {c0.x, c0.y, c0.z, c0.w, c1.x, c1.y, c1.z, c1.w};

            double bv = INFINITY;
            int bj = TT;
            #pragma unroll
            for (int s = 0; s < SLOTS; ++s) {
                if (!((selbits >> s) & 1)) {
                    double r = ((mv + (double)cv[s]) - ui) - v_[s];
                    if (r < key[s]) {
                        key[s] = r;
                        P2 p; p.i = i; p.j = jc;
                        sm.l.path2[s * NT + tid] = p;
                    }
                    double kk = key[s];
                    if (kk < bv) { bv = kk; bj = jbase + s; }
                }
            }
            dpp_lexmin<0x111>(bv, bj);
            dpp_lexmin<0x112>(bv, bj);
            dpp_lexmin<0x114>(bv, bj);
            dpp_lexmin<0x118>(bv, bj);
            dpp_lexmin<0x142>(bv, bj);
            dpp_lexmin<0x143>(bv, bj);
            int rlo = __builtin_amdgcn_readlane(__double2loint(bv), 63);
            int rhi = __builtin_amdgcn_readlane(__double2hiint(bv), 63);
            double wv = __hiloint2double(rhi, rlo);
            int wj = __builtin_amdgcn_readlane(bj, 63);

            par ^= 1;
            if (lane == 0) {
                Cand c; c.v = wv; c.j = wj; c.pad = 0;
                sm.l.cand[par][wave] = c;
            }
            __syncthreads();

            Cand cc = sm.l.cand[par][0];
            double MV = cc.v; int BJ = cc.j;
            #pragma unroll
            for (int w = 1; w < 4; ++w) {
                Cand c2 = sm.l.cand[par][w];
                if (c2.v < MV || (c2.v == MV && c2.j < BJ)) { MV = c2.v; BJ = c2.j; }
            }
            mv = MV;
            if ((BJ >> 3) == tid) selbits |= 1 << (BJ & 7);
            if (tid == 0) sm.l.selj[L] = BJ;

            URow ur = sm.l.urow[BJ];
            if (ur.row < 0) { sink = BJ; break; }
            if (tid == 0) { sm.l.selm[L] = MV; sm.l.selrow[L] = ur.row; }
            i = ur.row; ui = ur.u; jc = BJ;
            L++;
            const float* crow = cb + (size_t)i * TT + jbase;
            c0 = *(const float4*)crow;
            c1 = *(const float4*)(crow + 4);
        }

        double M = mv;
        #pragma unroll
        for (int s = 0; s < SLOTS; ++s)
            if ((selbits >> s) & 1) v_[s] = v_[s] - (M - key[s]);
        for (int k = tid; k < L; k += NT)
            sm.l.u[sm.l.selrow[k]] = sm.l.u[sm.l.selrow[k]] + (M - sm.l.selm[k]);
        if (tid == 0) {
            sm.l.u[cur] = sm.l.u[cur] + M;
            int j = sink;
            while (true) {
                P2 p = sm.l.path2[(j & 7) * NT + (j >> 3)];
                int ii = p.i;
                sm.l.row4col[j] = ii;
                sm.l.col4row[ii] = j;
                if (ii == cur) break;
                j = p.j;
            }
        }
        __syncthreads();
        if (tid <= L) {
            int j = sm.l.selj[tid];
            int r = sm.l.row4col[j];
            URow t; t.u = sm.l.u[r]; t.row = r; t.pad = 0;
            sm.l.urow[j] = t;
        }
        __syncthreads();
    }

    // order = argsort(col4row); pred_idx = col4row[order]; tgt_idx = order
    if (tid < OO) {
        int my = sm.l.col4row[tid];
        int rank = 0;
        for (int o = 0; o < OO; ++o) rank += (sm.l.col4row[o] < my) ? 1 : 0;
        out[(size_t)b * OO + rank] = my;         // pred_idx
        out[(size_t)(BB + b) * OO + rank] = tid; // tgt_idx
    }
}

// ---------------------------------------------------------------------------
extern "C" void kernel_launch(void* const* d_in, const int* in_sizes, int n_in,
                              void* d_out, int out_size, void* d_ws, size_t ws_size,
                              hipStream_t stream) {
    const float* pred_bboxes = (const float*)d_in[0];    // [B,T,4]
    const float* target_bboxes = (const float*)d_in[1];  // [B,O,4]
    const float* pred_classes = (const float*)d_in[2];   // [B,T,C]
    const int* target_classes = (const int*)d_in[3];     // [B,O]
    int* out = (int*)d_out;                              // [2,B,O] int32

    float* cost = (float*)d_ws;  // [B][O][T] fp32 (32 MB)
    unsigned long long* rowmins =
        (unsigned long long*)(cost + (size_t)BB * OO * TT);  // [B][NTILE][O]
    int* cnt = (int*)(rowmins + (size_t)BB * NTILE * OO);    // [B]

    hipMemsetAsync(cnt, 0, BB * sizeof(int), stream);        // d_ws is 0xAA-poisoned

    hung_fused_kernel<<<BB * NTILE, NT, 0, stream>>>(
        pred_bboxes, target_bboxes, pred_classes, target_classes,
        cost, rowmins, cnt, out);
}

// Round 11
// 260.109 us; speedup vs baseline: 1.2610x; 1.1128x over previous
//
#include <hip/hip_runtime.h>
#include <math.h>
#include <float.h>

// Problem dims (fixed by setup_inputs)
#define BB 32
#define TT 2048
#define OO 128
#define CC 80
#define EPSF 1e-7f
#define NT 256
#define SLOTS 8           // columns per thread in LSA
#define CPAD 81           // LDS class-row stride: 81%32=17, gcd(17,32)=1 -> conflict-free
#define TPT 128           // tokens per cost tile
#define NTILE 16          // cost t-tiles (TT/TPT)

typedef float vf4 __attribute__((ext_vector_type(4)));   // native vec for nontemporal

struct alignas(16) URow { double u; int row; int pad; };   // {u[row4col[j]], row4col[j]}
struct alignas(8)  P2   { int i; int j; };                 // path row, its prior column
struct alignas(16) Cand { double v; int j; int pad; };

// DPP lexicographic-min (val,idx): incoming lanes aggregate strictly-lower
// column ranges -> (tv <= bv) == first-index tie-break. Identity {+inf, MAX}.
template<int CTRL>
__device__ __forceinline__ void dpp_lexmin(double& bv, int& bj) {
    int lo = __double2loint(bv), hi = __double2hiint(bv);
    int tlo = __builtin_amdgcn_update_dpp(0, lo, CTRL, 0xF, 0xF, false);
    int thi = __builtin_amdgcn_update_dpp(0x7FF00000, hi, CTRL, 0xF, 0xF, false);
    int tj  = __builtin_amdgcn_update_dpp(0x7FFFFFFF, bj, CTRL, 0xF, 0xF, false);
    double tv = __hiloint2double(thi, tlo);
    if (tv <= bv) { bv = tv; bj = tj; }
}

// f32 (val,idx) lexmin for the cost phase's row-min reduction.
template<int CTRL>
__device__ __forceinline__ void dpp_lexmin_f32(float& bv, int& bj) {
    int tlo = __builtin_amdgcn_update_dpp(0x7F800000, __float_as_int(bv), CTRL, 0xF, 0xF, false);
    int tj  = __builtin_amdgcn_update_dpp(0x7FFFFFFF, bj, CTRL, 0xF, 0xF, false);
    float tv = __int_as_float(tlo);
    if (tv < bv || (tv == bv && tj < bj)) { bv = tv; bj = tj; }
}

// LDS is phase-exclusive: cost staging first, LSA state after.
// Union max ~69 KB -> 2 blocks/CU (the occupancy lever for the cost phase).
union SM {
    struct {
        float  xv[TPT * CPAD];                     // 41472 B
        float4 box[OO];                            // {x1,y1,x2,y2}
        float2 wt[OO];                             // {w2h2, tc-as-float-bits}
        unsigned long long rmin[OO * 2];
    } c;
    struct {
        URow   urow[TT];
        P2     path2[TT];                          // swizzled
        int    row4col[TT];
        int    claim[TT];
        int    col4row[OO];
        double u[OO];
        int    amin[OO];
        int    flag[OO];
        int    freelist[OO];
        int    selj[OO + 8];
        double selm[OO + 8];
        int    selrow[OO + 8];
        Cand   cand[2][4];
        int    nfree;
    } l;
};

// ---------------------------------------------------------------------------
// Fused kernel, XCD-matched mapping: b = bx&31, tile = bx>>5 (all of batch
// b's blocks share bx%8 -> same XCD under round-robin). 512 producer blocks
// each do a 128-token cost tile (2 threads/token: tid&127 = token,
// tid>>7 = o-half); tile-0 blocks then acquire-spin on cnt[b]==16 and run
// the round-6 JV LSA (greedy tight pre-assignment + Dijkstra SAP).
// ---------------------------------------------------------------------------
__global__ __launch_bounds__(NT) void hung_fused_kernel(
    const float* __restrict__ pb, const float* __restrict__ tb,
    const float* __restrict__ cls, const int* __restrict__ tcls,
    float* __restrict__ cost, unsigned long long* __restrict__ rowmins,
    int* __restrict__ cnt, int* __restrict__ out) {
#pragma clang fp contract(off)
    __shared__ SM sm;

    int bx = blockIdx.x;
    int b = bx & 31;
    int tile = bx >> 5;
    int t0 = tile * TPT;
    int tid = threadIdx.x;
    int lane = tid & 63;
    int wave = tid >> 6;
    int tok = tid & (TPT - 1);
    int oh = tid >> 7;           // o-half: 0 -> o in [0,64), 1 -> [64,128)

    // ======================= Phase 1: cost tile =======================
    {
        // stage class tile (nontemporal: read-once, keep L2 for cost writes)
        const float* cbase = cls + ((size_t)b * TT + t0) * CC;
        #pragma unroll
        for (int k = 0; k < (TPT * CC) / (NT * 4); ++k) {   // 10 iters
            int idx4 = (k * NT + tid) * 4;
            vf4 vv = __builtin_nontemporal_load((const vf4*)(cbase + idx4));
            int r = idx4 / CC;
            int c = idx4 - r * CC;
            float* dst = &sm.c.xv[r * CPAD + c];
            dst[0] = vv.x; dst[1] = vv.y; dst[2] = vv.z; dst[3] = vv.w;
        }
        if (tid < OO) {
            float4 tbox = ((const float4*)tb)[b * OO + tid];
            float x1 = tbox.x - tbox.z / 2.f;
            float y1 = tbox.y - tbox.w / 2.f;
            float x2 = tbox.x + tbox.z / 2.f;
            float y2 = tbox.y + tbox.w / 2.f;
            float4 bb; bb.x = x1; bb.y = y1; bb.z = x2; bb.w = y2;
            sm.c.box[tid] = bb;
            float w2 = x2 - x1;
            float h2 = (y2 - y1) + EPSF;
            float2 wt; wt.x = w2 * h2;
            wt.y = __int_as_float(tcls[b * OO + tid]);
            sm.c.wt[tid] = wt;
        }
        __syncthreads();

        size_t bt = (size_t)b * TT + t0 + tok;
        float4 pbox = ((const float4*)pb)[bt];
        float b1x1 = pbox.x - pbox.z / 2.f;
        float b1y1 = pbox.y - pbox.w / 2.f;
        float b1x2 = pbox.x + pbox.z / 2.f;
        float b1y2 = pbox.y + pbox.w / 2.f;
        float w1 = b1x2 - b1x1;
        float h1 = (b1y2 - b1y1) + EPSF;
        float w1h1 = w1 * h1;

        // softmax normalizers (both o-half threads compute identically;
        // sequential op order -> bit-identical to reference)
        const float* xr = &sm.c.xv[tok * CPAD];
        float m = xr[0];
        #pragma unroll
        for (int c = 1; c < CC; ++c) m = fmaxf(m, xr[c]);
        float ssum = 0.f;
        #pragma unroll
        for (int c = 0; c < CC; ++c) ssum += expf(xr[c] - m);
        float ls = logf(ssum);

        float* cbt = cost + (size_t)b * OO * TT + t0;
        for (int k = 0; k < OO / 2; ++k) {
            int o = oh * (OO / 2) + k;
            float4 bb = sm.c.box[o];        // one b128 broadcast per wave
            float2 wt = sm.c.wt[o];
            float b2x1 = bb.x, b2y1 = bb.y, b2x2 = bb.z, b2y2 = bb.w;
            float iw = fminf(b1x2, b2x2) - fmaxf(b1x1, b2x1);
            float ih = fminf(b1y2, b2y2) - fmaxf(b1y1, b2y1);
            iw = fmaxf(iw, 0.f);
            ih = fmaxf(ih, 0.f);
            float inter = iw * ih;
            float uni = ((w1h1 + wt.x) - inter) + EPSF;
            float iou = inter / uni;
            float cw = fmaxf(b1x2, b2x2) - fminf(b1x1, b2x1);
            float ch = fmaxf(b1y2, b2y2) - fminf(b1y1, b2y1);
            float c_area = (cw * ch) + EPSF;
            float giou = iou - (c_area - uni) / c_area;
            float bbox_loss = 1.0f - giou;

            float xc = xr[__float_as_int(wt.y)];   // conflict-free (stride 81)
            float shifted = xc - m;
            float cls_neg = -(shifted - ls);

            float cval = bbox_loss + cls_neg;
            cbt[(size_t)o * TT + tok] = cval;

            // per-(b,o) wave min/argmin over this wave's 64 tokens
            float bvv = cval;
            int bjj = t0 + tok;
            dpp_lexmin_f32<0x111>(bvv, bjj);
            dpp_lexmin_f32<0x112>(bvv, bjj);
            dpp_lexmin_f32<0x114>(bvv, bjj);
            dpp_lexmin_f32<0x118>(bvv, bjj);
            dpp_lexmin_f32<0x142>(bvv, bjj);
            dpp_lexmin_f32<0x143>(bvv, bjj);
            if (lane == 63)
                sm.c.rmin[o * 2 + (wave & 1)] =
                    ((unsigned long long)__float_as_uint(bvv) << 32) | (unsigned)bjj;
        }
        __syncthreads();
        if (tid < OO) {
            unsigned long long r0 = sm.c.rmin[tid * 2 + 0];
            unsigned long long r1 = sm.c.rmin[tid * 2 + 1];
            rowmins[((size_t)b * NTILE + tile) * OO + tid] = r0 < r1 ? r0 : r1;
        }
        __syncthreads();   // drains vmcnt(0): all global stores issued
        if (tid == 0)      // agent-scope release: cost+rowmins visible first
            __hip_atomic_fetch_add(&cnt[b], 1, __ATOMIC_RELEASE,
                                   __HIP_MEMORY_SCOPE_AGENT);
    }

    if (tile != 0) return;   // 480 producer-only blocks exit

    // ============ Phase 2 (tile-0 blocks): wait for siblings ============
    if (tid == 0) {
        while (__hip_atomic_load(&cnt[b], __ATOMIC_ACQUIRE,
                                 __HIP_MEMORY_SCOPE_AGENT) < NTILE)
            __builtin_amdgcn_s_sleep(2);
    }
    __syncthreads();   // all threads see post-acquire state

    // ======================= Phase 3: LSA (round-6 core) =======================
    const float* cb = cost + (size_t)b * OO * TT;
    const int jbase = tid * SLOTS;

    double v_[SLOTS];
    double key[SLOTS];
    #pragma unroll
    for (int s = 0; s < SLOTS; ++s) v_[s] = 0.0;

    // ---- Phase A: u = row minima (combine the 16 tile results) ----
    if (tid < OO) {
        const unsigned long long* p = rowmins + (size_t)b * NTILE * OO + tid;
        unsigned long long best = p[0];
        #pragma unroll
        for (int t = 1; t < NTILE; ++t) {
            unsigned long long x = p[t * OO];
            if (x < best) best = x;
        }
        sm.l.u[tid] = (double)__uint_as_float((unsigned)(best >> 32));
        sm.l.amin[tid] = (int)(best & 0xFFFFFFFFull);
        sm.l.col4row[tid] = -1;
    }
    for (int j = tid; j < TT; j += NT) { sm.l.row4col[j] = -1; sm.l.claim[j] = 0x7FFFFFFF; }
    __syncthreads();

    // ---- Phase B: greedy tight pre-assignment (lowest row wins) ----
    if (tid < OO) atomicMin(&sm.l.claim[sm.l.amin[tid]], tid);
    __syncthreads();
    if (tid < OO) {
        int j = sm.l.amin[tid];
        if (sm.l.claim[j] == tid) { sm.l.col4row[tid] = j; sm.l.row4col[j] = tid; }
    }
    __syncthreads();

    // ---- Phase C: urow init + free-row list ----
    for (int j = tid; j < TT; j += NT) {
        int r = sm.l.row4col[j];
        URow t; t.row = r; t.u = (r >= 0) ? sm.l.u[r] : 0.0; t.pad = 0;
        sm.l.urow[j] = t;
    }
    if (tid < OO) sm.l.flag[tid] = (sm.l.col4row[tid] < 0) ? 1 : 0;
    __syncthreads();
    if (tid < OO && sm.l.flag[tid]) {
        int rank = 0;
        for (int o = 0; o < tid; ++o) rank += sm.l.flag[o];
        sm.l.freelist[rank] = tid;
    }
    if (tid == 0) {
        int nf = 0;
        for (int o = 0; o < OO; ++o) nf += sm.l.flag[o];
        sm.l.nfree = nf;
    }
    __syncthreads();
    int nfree = sm.l.nfree;

    // root-row prefetch for the first Dijkstra
    float4 pf0, pf1;
    if (nfree > 0) {
        const float* rr = cb + (size_t)sm.l.freelist[0] * TT + jbase;
        pf0 = *(const float4*)rr;
        pf1 = *(const float4*)(rr + 4);
    }

    // ---- Phase D: Dijkstra SAP ----
    int par = 0;
    for (int fi = 0; fi < nfree; ++fi) {
        int cur = sm.l.freelist[fi];

        #pragma unroll
        for (int s = 0; s < SLOTS; ++s) key[s] = INFINITY;
        int selbits = 0;
        double mv = 0.0;
        int i = cur, jc = -1;
        double ui = sm.l.u[cur];
        float4 c0 = pf0, c1 = pf1;
        int L = 0, sink;

        while (true) {
            float cv[SLOTS] = {c0.x, c0.y, c0.z, c0.w, c1.x, c1.y, c1.z, c1.w};
            double D = ui - mv;   // wave-uniform; one dependent op hoisted

            double bv = INFINITY;
            int bj = TT;
            #pragma unroll
            for (int s = 0; s < SLOTS; ++s) {
                if (!((selbits >> s) & 1)) {
                    double r = ((double)cv[s] - D) - v_[s];
                    if (r < key[s]) {
                        key[s] = r;
                        P2 p; p.i = i; p.j = jc;
                        sm.l.path2[s * NT + tid] = p;
                    }
                    double kk = key[s];
                    if (kk < bv) { bv = kk; bj = jbase + s; }
                }
            }
            dpp_lexmin<0x111>(bv, bj);
            dpp_lexmin<0x112>(bv, bj);
            dpp_lexmin<0x114>(bv, bj);
            dpp_lexmin<0x118>(bv, bj);
            dpp_lexmin<0x142>(bv, bj);
            dpp_lexmin<0x143>(bv, bj);
            int rlo = __builtin_amdgcn_readlane(__double2loint(bv), 63);
            int rhi = __builtin_amdgcn_readlane(__double2hiint(bv), 63);
            double wv = __hiloint2double(rhi, rlo);
            int wj = __builtin_amdgcn_readlane(bj, 63);

            par ^= 1;
            if (lane == 0) {
                Cand c; c.v = wv; c.j = wj; c.pad = 0;
                sm.l.cand[par][wave] = c;
            }
            __syncthreads();

            // read all 4 candidates AND their urow entries up front (the 4
            // urow broadcasts overlap the combine instead of following it)
            Cand cc0 = sm.l.cand[par][0];
            Cand cc1 = sm.l.cand[par][1];
            Cand cc2 = sm.l.cand[par][2];
            Cand cc3 = sm.l.cand[par][3];
            URow u0 = sm.l.urow[cc0.j];
            URow u1 = sm.l.urow[cc1.j];
            URow u2 = sm.l.urow[cc2.j];
            URow u3 = sm.l.urow[cc3.j];
            double MV = cc0.v; int BJ = cc0.j; URow UW = u0;
            if (cc1.v < MV || (cc1.v == MV && cc1.j < BJ)) { MV = cc1.v; BJ = cc1.j; UW = u1; }
            if (cc2.v < MV || (cc2.v == MV && cc2.j < BJ)) { MV = cc2.v; BJ = cc2.j; UW = u2; }
            if (cc3.v < MV || (cc3.v == MV && cc3.j < BJ)) { MV = cc3.v; BJ = cc3.j; UW = u3; }
            mv = MV;
            if ((BJ >> 3) == tid) selbits |= 1 << (BJ & 7);
            if (tid == 0) sm.l.selj[L] = BJ;

            if (UW.row < 0) { sink = BJ; break; }
            if (tid == 0) { sm.l.selm[L] = MV; sm.l.selrow[L] = UW.row; }
            i = UW.row; ui = UW.u; jc = BJ;
            L++;
            const float* crow = cb + (size_t)i * TT + jbase;
            c0 = *(const float4*)crow;
            c1 = *(const float4*)(crow + 4);
        }

        // prefetch next Dijkstra's root row (off the critical path)
        if (fi + 1 < nfree) {
            const float* rr = cb + (size_t)sm.l.freelist[fi + 1] * TT + jbase;
            pf0 = *(const float4*)rr;
            pf1 = *(const float4*)(rr + 4);
        }

        double M = mv;
        #pragma unroll
        for (int s = 0; s < SLOTS; ++s)
            if ((selbits >> s) & 1) v_[s] = v_[s] - (M - key[s]);
        for (int k = tid; k < L; k += NT)
            sm.l.u[sm.l.selrow[k]] = sm.l.u[sm.l.selrow[k]] + (M - sm.l.selm[k]);
        if (tid == 0) {
            sm.l.u[cur] = sm.l.u[cur] + M;
            int j = sink;
            while (true) {
                P2 p = sm.l.path2[(j & 7) * NT + (j >> 3)];
                int ii = p.i;
                sm.l.row4col[j] = ii;
                sm.l.col4row[ii] = j;
                if (ii == cur) break;
                j = p.j;
            }
        }
        __syncthreads();
        if (tid <= L) {
            int j = sm.l.selj[tid];
            int r = sm.l.row4col[j];
            URow t; t.u = sm.l.u[r]; t.row = r; t.pad = 0;
            sm.l.urow[j] = t;
        }
        __syncthreads();
    }

    // order = argsort(col4row); pred_idx = col4row[order]; tgt_idx = order
    if (tid < OO) {
        int my = sm.l.col4row[tid];
        int rank = 0;
        for (int o = 0; o < OO; ++o) rank += (sm.l.col4row[o] < my) ? 1 : 0;
        out[(size_t)b * OO + rank] = my;         // pred_idx
        out[(size_t)(BB + b) * OO + rank] = tid; // tgt_idx
    }
}

// ---------------------------------------------------------------------------
extern "C" void kernel_launch(void* const* d_in, const int* in_sizes, int n_in,
                              void* d_out, int out_size, void* d_ws, size_t ws_size,
                              hipStream_t stream) {
    const float* pred_bboxes = (const float*)d_in[0];    // [B,T,4]
    const float* target_bboxes = (const float*)d_in[1];  // [B,O,4]
    const float* pred_classes = (const float*)d_in[2];   // [B,T,C]
    const int* target_classes = (const int*)d_in[3];     // [B,O]
    int* out = (int*)d_out;                              // [2,B,O] int32

    float* cost = (float*)d_ws;  // [B][O][T] fp32 (32 MB)
    unsigned long long* rowmins =
        (unsigned long long*)(cost + (size_t)BB * OO * TT);  // [B][NTILE][O]
    int* cnt = (int*)(rowmins + (size_t)BB * NTILE * OO);    // [B]

    (void)hipMemsetAsync(cnt, 0, BB * sizeof(int), stream);  // d_ws is 0xAA-poisoned

    hung_fused_kernel<<<BB * NTILE, NT, 0, stream>>>(
        pred_bboxes, target_bboxes, pred_classes, target_classes,
        cost, rowmins, cnt, out);
}